// Round 3
// baseline (459.404 us; speedup 1.0000x reference)
//
#include <hip/hip_runtime.h>

#define TGT 2048
#define SRC 2048
#define BH 16
#define HD 64
#define BT 16
#define SROW 2056  // shorts per LDS S row (2048 + 8 pad, 16B-aligned rows)

typedef __bf16 bf16x8 __attribute__((ext_vector_type(8)));
typedef unsigned short ushortx8 __attribute__((ext_vector_type(8)));
typedef float floatx4 __attribute__((ext_vector_type(4)));

__device__ int g_mask_is_u8;

__device__ __forceinline__ unsigned short f2bf(float f) {
  unsigned u = __builtin_bit_cast(unsigned, f);
  u += 0x7FFFu + ((u >> 16) & 1u);   // RNE
  return (unsigned short)(u >> 16);
}
__device__ __forceinline__ float bf2f(unsigned short s) {
  unsigned u = ((unsigned)s) << 16;
  return __builtin_bit_cast(float, u);
}

// ---- single prologue kernel: cvt Q/K (blocks 0..2047), V-transpose
// (blocks 2048..2559), mask-format detect (block 2560) ----
__global__ void prep(const float* __restrict__ q, const float* __restrict__ k,
                     const float* __restrict__ v, const unsigned char* __restrict__ m,
                     unsigned short* __restrict__ qb, unsigned short* __restrict__ kb,
                     unsigned short* __restrict__ vt) {
  __shared__ unsigned short tile[64 * 72];
  __shared__ int any;
  const int b = blockIdx.x;
  const int tid = threadIdx.x;
  if (b < 2048) {
    const int gid = b * 256 + tid;
    const int half = TGT * BH * HD / 8;
    const float* src; unsigned short* dst; float sc; int idx;
    if (gid < half) { src = q; dst = qb; sc = 0.125f; idx = gid; }
    else            { src = k; dst = kb; sc = 1.0f;  idx = gid - half; }
    const float* p = src + (size_t)idx * 8;
    float4 a = *(const float4*)p;
    float4 bb = *(const float4*)(p + 4);
    union { unsigned short u[8]; ushortx8 v; } o;
    o.u[0] = f2bf(a.x * sc); o.u[1] = f2bf(a.y * sc);
    o.u[2] = f2bf(a.z * sc); o.u[3] = f2bf(a.w * sc);
    o.u[4] = f2bf(bb.x * sc); o.u[5] = f2bf(bb.y * sc);
    o.u[6] = f2bf(bb.z * sc); o.u[7] = f2bf(bb.w * sc);
    *(ushortx8*)(dst + (size_t)idx * 8) = o.v;
  } else if (b < 2560) {
    const int bb = b - 2048;
    const int h = bb >> 5;
    const int s0 = (bb & 31) * 64;
    const int sr = tid >> 4, c = tid & 15;
#pragma unroll
    for (int p = 0; p < 4; ++p) {
      const int s = sr + p * 16;
      float4 f = *(const float4*)(v + (size_t)(s0 + s) * (BH * HD) + h * HD + c * 4);
      tile[(c * 4 + 0) * 72 + s] = f2bf(f.x);
      tile[(c * 4 + 1) * 72 + s] = f2bf(f.y);
      tile[(c * 4 + 2) * 72 + s] = f2bf(f.z);
      tile[(c * 4 + 3) * 72 + s] = f2bf(f.w);
    }
    __syncthreads();
    const int d = tid >> 2, q4 = tid & 3;
    ushortx8 o0 = *(const ushortx8*)&tile[d * 72 + q4 * 16];
    ushortx8 o1 = *(const ushortx8*)&tile[d * 72 + q4 * 16 + 8];
    unsigned short* dst = vt + (size_t)h * HD * SRC + (size_t)d * SRC + s0 + q4 * 16;
    *(ushortx8*)dst = o0;
    *(ushortx8*)(dst + 8) = o1;
  } else {
    if (tid == 0) any = 0;
    __syncthreads();
    int local = 0;
    int base = tid * 16;
#pragma unroll
    for (int i = 0; i < 16; ++i) {
      int idx = base + i;
      if (idx & 3) local |= m[idx];
    }
    if (local) atomicOr(&any, 1);
    __syncthreads();
    if (tid == 0) g_mask_is_u8 = (any != 0);
  }
}

// ---- main attention kernel: 512 threads, register-resident softmax ----
__launch_bounds__(512, 4)
__global__ void attn_kernel(const unsigned short* __restrict__ qb,
                            const unsigned short* __restrict__ kb,
                            const unsigned short* __restrict__ vtb,
                            const unsigned char* __restrict__ mask8,
                            const int* __restrict__ mask32,
                            float* __restrict__ out0,
                            float* __restrict__ wout) {
  extern __shared__ char smem[];
  unsigned short* smS = (unsigned short*)smem;           // [BT][SROW] bf16 e-values
  float* redArr = (float*)(smem + BT * SROW * 2);        // [1024] reduce + D-combine
  float* rowmaxArr = redArr + 1024;                      // [16]
  float* invArr = rowmaxArr + BT;                        // [16]

  const int bid = blockIdx.x;
  const int h = bid >> 7;
  const int t0 = (bid & 127) * BT;
  const int tid = threadIdx.x;
  const int wv = tid >> 6;
  const int lane = tid & 63;
  const int quad = lane >> 4;
  const int l16 = lane & 15;
  const bool is_u8 = (g_mask_is_u8 != 0);

  // Q fragments (bf16, pre-scaled by 1/8)
  bf16x8 aq[2];
  {
    const unsigned short* qp = qb + (size_t)(t0 + l16) * (BH * HD) + h * HD + quad * 8;
    aq[0] = __builtin_bit_cast(bf16x8, *(const ushortx8*)qp);
    aq[1] = __builtin_bit_cast(bf16x8, *(const ushortx8*)(qp + 32));
  }

  // ---- Phase B: S = QK^T, mask inline, keep packed bf16 in 32 VGPRs ----
  // lane owns (rows quad*4+r, cols st*16+l16) for st = wv + 8*ki, ki=0..15
  float rmax[4] = {-3.4e38f, -3.4e38f, -3.4e38f, -3.4e38f};
  unsigned pk[32];   // [pair=ki>>1][r]: lo=even ki, hi=odd ki
#pragma unroll
  for (int ki = 0; ki < 16; ++ki) {
    const int st = wv + ki * 8;
    const int sbase = st * 16;
    const unsigned short* kp = kb + (size_t)(sbase + l16) * (BH * HD) + h * HD + quad * 8;
    bf16x8 bk0 = __builtin_bit_cast(bf16x8, *(const ushortx8*)kp);
    bf16x8 bk1 = __builtin_bit_cast(bf16x8, *(const ushortx8*)(kp + 32));
    floatx4 c = {0.f, 0.f, 0.f, 0.f};
    c = __builtin_amdgcn_mfma_f32_16x16x32_bf16(aq[0], bk0, c, 0, 0, 0);
    c = __builtin_amdgcn_mfma_f32_16x16x32_bf16(aq[1], bk1, c, 0, 0, 0);
    const int scol = sbase + l16;
#pragma unroll
    for (int r = 0; r < 4; ++r) {
      const size_t midx = (size_t)(t0 + quad * 4 + r) * SRC + scol;
      const int mv = is_u8 ? (int)mask8[midx] : mask32[midx];
      const float val = mv ? -1e8f : c[r];
      rmax[r] = fmaxf(rmax[r], val);
      const unsigned bb = (unsigned)f2bf(val);
      const int pi = (ki >> 1) * 4 + r;
      if (ki & 1) pk[pi] |= (bb << 16); else pk[pi] = bb;
    }
  }

  // row max: shuffle within 16-lane group, then cross-wave via LDS
#pragma unroll
  for (int off = 1; off < 16; off <<= 1)
#pragma unroll
    for (int r = 0; r < 4; ++r) rmax[r] = fmaxf(rmax[r], __shfl_xor(rmax[r], off));
  if (l16 == 0) {
#pragma unroll
    for (int r = 0; r < 4; ++r) redArr[(quad * 4 + r) * 8 + wv] = rmax[r];
  }
  __syncthreads();
  if (tid < BT) {
    float m = redArr[tid * 8];
#pragma unroll
    for (int j = 1; j < 8; ++j) m = fmaxf(m, redArr[tid * 8 + j]);
    rowmaxArr[tid] = m;
  }
  __syncthreads();

  // ---- pass 2: e = exp(S - rowmax) in regs, row sums ----
  float rsum[4] = {0.f, 0.f, 0.f, 0.f};
  {
    float rm[4];
#pragma unroll
    for (int r = 0; r < 4; ++r) rm[r] = rowmaxArr[quad * 4 + r];
#pragma unroll
    for (int pi = 0; pi < 32; ++pi) {
      const int r = pi & 3;
      const unsigned p = pk[pi];
      const float e0 = __expf(bf2f((unsigned short)(p & 0xFFFF)) - rm[r]);
      const float e1 = __expf(bf2f((unsigned short)(p >> 16)) - rm[r]);
      rsum[r] += e0 + e1;
      pk[pi] = (unsigned)f2bf(e0) | ((unsigned)f2bf(e1) << 16);
    }
  }
#pragma unroll
  for (int off = 1; off < 16; off <<= 1)
#pragma unroll
    for (int r = 0; r < 4; ++r) rsum[r] += __shfl_xor(rsum[r], off);
  if (l16 == 0) {
#pragma unroll
    for (int r = 0; r < 4; ++r) redArr[(quad * 4 + r) * 8 + wv] = rsum[r];
  }
  __syncthreads();
  if (tid < BT) {
    float s = 0.f;
#pragma unroll
    for (int j = 0; j < 8; ++j) s += redArr[tid * 8 + j];
    invArr[tid] = 1.0f / s;
  }
  __syncthreads();

  // ---- pass 3: w = e*inv -> global (coalesced 64B/quad); e bf16 -> LDS ----
  {
    float iv[4];
#pragma unroll
    for (int r = 0; r < 4; ++r) iv[r] = invArr[quad * 4 + r];
#pragma unroll
    for (int pi = 0; pi < 32; ++pi) {
      const int r = pi & 3;
      const int pair = pi >> 2;
      const int col0 = wv * 16 + pair * 256 + l16;   // even-ki column
      const unsigned p = pk[pi];
      const unsigned short b0 = (unsigned short)(p & 0xFFFF);
      const unsigned short b1 = (unsigned short)(p >> 16);
      float* wr = wout + ((size_t)h * TGT + t0 + quad * 4 + r) * SRC;
      wr[col0] = bf2f(b0) * iv[r];
      wr[col0 + 128] = bf2f(b1) * iv[r];
      unsigned short* sr = smS + (quad * 4 + r) * SROW;
      sr[col0] = b0;
      sr[col0 + 128] = b1;
    }
  }
  __syncthreads();

  // ---- Phase D: out = (e V) * inv; wave = (s-half, d-tile) ----
  {
    const int dt = wv & 3;
    const int halfsel = wv >> 2;
    const int dbase = dt * 16;
    const int sstart = halfsel * 1024;
    const unsigned short* vp = vtb + (size_t)h * HD * SRC +
                               (size_t)(dbase + l16) * SRC + sstart + quad * 8;
    const unsigned short* sp = smS + l16 * SROW + sstart + quad * 8;
    floatx4 acc = {0.f, 0.f, 0.f, 0.f};
    for (int s0 = 0; s0 < 1024; s0 += 32) {
      bf16x8 af = __builtin_bit_cast(bf16x8, *(const ushortx8*)(sp + s0));
      bf16x8 bfv = __builtin_bit_cast(bf16x8, *(const ushortx8*)(vp + s0));
      acc = __builtin_amdgcn_mfma_f32_16x16x32_bf16(af, bfv, acc, 0, 0, 0);
    }
    if (halfsel) {
#pragma unroll
      for (int r = 0; r < 4; ++r)
        redArr[dt * 256 + (quad * 4 + r) * 16 + l16] = acc[r];
    }
    __syncthreads();
    if (!halfsel) {
#pragma unroll
      for (int r = 0; r < 4; ++r) {
        const int tl = quad * 4 + r;
        float s = acc[r] + redArr[dt * 256 + tl * 16 + l16];
        out0[((size_t)(t0 + tl) * BH + h) * HD + dbase + l16] = s * invArr[tl];
      }
    }
  }
}

extern "C" void kernel_launch(void* const* d_in, const int* in_sizes, int n_in,
                              void* d_out, int out_size, void* d_ws, size_t ws_size,
                              hipStream_t stream) {
  const float* q = (const float*)d_in[0];
  const float* k = (const float*)d_in[1];
  const float* v = (const float*)d_in[2];
  const unsigned char* m8 = (const unsigned char*)d_in[3];
  const int* m32 = (const int*)d_in[3];
  float* out0 = (float*)d_out;
  float* wout = out0 + (size_t)TGT * BH * HD;

  unsigned short* qb = (unsigned short*)d_ws;                 // 4 MB
  unsigned short* kb = qb + (size_t)TGT * BH * HD;            // 4 MB
  unsigned short* vt = kb + (size_t)SRC * BH * HD;            // 4 MB

  const size_t shbytes = (size_t)BT * SROW * 2 + 1024 * 4 + BT * 4 + BT * 4;
  hipFuncSetAttribute((const void*)attn_kernel,
                      hipFuncAttributeMaxDynamicSharedMemorySize, (int)shbytes);

  prep<<<dim3(2561), dim3(256), 0, stream>>>(q, k, v, m8, qb, kb, vt);
  attn_kernel<<<dim3(BH * (TGT / BT)), dim3(512), shbytes, stream>>>(
      qb, kb, vt, m8, m32, out0, wout);
}